// Round 1
// baseline (5595.738 us; speedup 1.0000x reference)
//
#include <hip/hip_runtime.h>
#include <math.h>

// Sizes fixed by the problem.
#define R_ 64
#define S_ 32
#define W_ 64
#define H_ 256
#define UF_ 20

__device__ __forceinline__ float sigmoidf_(float x){ return 1.0f/(1.0f+expf(-x)); }
__device__ __forceinline__ float seluf_(float x){
  const float sc=1.0507009873554805f, al=1.6732632423543772f;
  return x>0.0f ? sc*x : sc*al*(expf(x)-1.0f);
}
__device__ __forceinline__ void fma4(float (&acc)[4], float a, const float4 b){
  acc[0]+=a*b.x; acc[1]+=a*b.y; acc[2]+=a*b.z; acc[3]+=a*b.w;
}

// ---------------------------------------------------------------------------
// Word-level GRU, one timestep, both directions. Fused: embedding gather +
// x-GEMM + h-GEMM + gate nonlinearities + h update. BM=32 sentences,
// BH=64 hidden units per block; grid (64, 4, 2).
// ---------------------------------------------------------------------------
__global__ __launch_bounds__(256) void word_step(
    int t,
    const int*   __restrict__ toks,  const float* __restrict__ embed,
    const float* __restrict__ wih,   const float* __restrict__ whh,
    const float* __restrict__ bih,   const float* __restrict__ bhh,
    const float* __restrict__ hcur,  float* __restrict__ hnxt)
{
  const int d   = blockIdx.z;
  const int b0  = blockIdx.x * 32;
  const int j0  = blockIdx.y * 64;
  const int tid = threadIdx.x;

  __shared__ float As[16][36];        // [k][m], padded
  __shared__ float Bs[3][16][68];     // [gate][k][j], padded
  __shared__ int   tok[32];

  const int tx = (d == 0) ? t : (W_ - 1 - t);
  if (tid < 32) tok[tid] = toks[(b0 + tid) * W_ + tx];
  __syncthreads();

  float accR[2][4]  = {{0}}, accZ[2][4] = {{0}};
  float accNX[2][4] = {{0}}, accNH[2][4] = {{0}};

  const int mloc = (tid >> 4) << 1;   // 0..30
  const int nloc = (tid & 15) << 2;   // 0..60
  const float* hbase = hcur + (size_t)d * 2048 * H_;

  const int am = tid >> 2;            // A stage: tid<128 -> am 0..31
  const int ak = (tid & 3) << 2;
  const int bn = tid >> 2;            // B stage: 0..63
  const int bk = (tid & 3) << 2;

#pragma unroll
  for (int p = 0; p < 2; p++) {
    const float* wsrc = (p == 0 ? wih : whh) + (size_t)d * 768 * H_;
    for (int k0 = 0; k0 < H_; k0 += 16) {
      float4 a4 = make_float4(0,0,0,0);
      if (tid < 128) {
        if (p == 0) a4 = *(const float4*)&embed[(size_t)tok[am] * H_ + (k0 + ak)];
        else        a4 = *(const float4*)&hbase[(size_t)(b0 + am) * H_ + (k0 + ak)];
      }
      float4 bq0 = *(const float4*)&wsrc[(size_t)(0*H_ + j0 + bn) * H_ + (k0 + bk)];
      float4 bq1 = *(const float4*)&wsrc[(size_t)(1*H_ + j0 + bn) * H_ + (k0 + bk)];
      float4 bq2 = *(const float4*)&wsrc[(size_t)(2*H_ + j0 + bn) * H_ + (k0 + bk)];
      __syncthreads();
      if (tid < 128) {
        As[ak+0][am]=a4.x; As[ak+1][am]=a4.y; As[ak+2][am]=a4.z; As[ak+3][am]=a4.w;
      }
      Bs[0][bk+0][bn]=bq0.x; Bs[0][bk+1][bn]=bq0.y; Bs[0][bk+2][bn]=bq0.z; Bs[0][bk+3][bn]=bq0.w;
      Bs[1][bk+0][bn]=bq1.x; Bs[1][bk+1][bn]=bq1.y; Bs[1][bk+2][bn]=bq1.z; Bs[1][bk+3][bn]=bq1.w;
      Bs[2][bk+0][bn]=bq2.x; Bs[2][bk+1][bn]=bq2.y; Bs[2][bk+2][bn]=bq2.z; Bs[2][bk+3][bn]=bq2.w;
      __syncthreads();
#pragma unroll
      for (int k = 0; k < 16; k++) {
        const float a0 = As[k][mloc], a1 = As[k][mloc+1];
        const float4 br  = *(const float4*)&Bs[0][k][nloc];
        const float4 bz  = *(const float4*)&Bs[1][k][nloc];
        const float4 bn4 = *(const float4*)&Bs[2][k][nloc];
        fma4(accR[0], a0, br);  fma4(accR[1], a1, br);
        fma4(accZ[0], a0, bz);  fma4(accZ[1], a1, bz);
        if (p == 0) { fma4(accNX[0], a0, bn4); fma4(accNX[1], a1, bn4); }
        else        { fma4(accNH[0], a0, bn4); fma4(accNH[1], a1, bn4); }
      }
    }
  }

  const float* bihd = bih + d * 768;
  const float* bhhd = bhh + d * 768;
  float* hout = hnxt + (size_t)d * 2048 * H_;
#pragma unroll
  for (int mi = 0; mi < 2; mi++) {
    const int b = b0 + mloc + mi;
    const float4 hp = *(const float4*)&hbase[(size_t)b * H_ + j0 + nloc];
    const float hpa[4] = {hp.x, hp.y, hp.z, hp.w};
    float o[4];
#pragma unroll
    for (int ji = 0; ji < 4; ji++) {
      const int j = j0 + nloc + ji;
      const float r = sigmoidf_(accR[mi][ji] + bihd[j]       + bhhd[j]);
      const float z = sigmoidf_(accZ[mi][ji] + bihd[256 + j] + bhhd[256 + j]);
      const float n = tanhf(accNX[mi][ji] + bihd[512 + j] + r * (accNH[mi][ji] + bhhd[512 + j]));
      o[ji] = (1.0f - z) * n + z * hpa[ji];
    }
    *(float4*)&hout[(size_t)b * H_ + j0 + nloc] = make_float4(o[0],o[1],o[2],o[3]);
  }
}

// ---------------------------------------------------------------------------
// Sentence-level GRU, one timestep, both directions. gx precomputed.
// BM=64 reviews (all), BH=16 units; grid (1, 16, 2).
// ---------------------------------------------------------------------------
__global__ __launch_bounds__(256) void sent_step(
    int t, const float* __restrict__ gx, const float* __restrict__ whh,
    const float* __restrict__ bih, const float* __restrict__ bhh,
    const float* __restrict__ hcur, float* __restrict__ hnxt)
{
  const int d   = blockIdx.z;
  const int j0  = blockIdx.y * 16;
  const int tid = threadIdx.x;
  __shared__ float As[16][68];
  __shared__ float Bs[3][16][20];

  float accR[4]={0}, accZ[4]={0}, accNH[4]={0};
  const int m_row = tid >> 2;           // 0..63 review
  const int nl    = (tid & 3) << 2;     // 0,4,8,12
  const float* hbase = hcur + (size_t)d * R_ * H_;
  const float* wsrc  = whh + (size_t)d * 768 * H_;

  const int am = tid >> 2, ak = (tid & 3) << 2;

  for (int k0 = 0; k0 < H_; k0 += 16) {
    const float4 a4 = *(const float4*)&hbase[(size_t)am * H_ + k0 + ak];
    float4 bq = make_float4(0,0,0,0);
    int bg = 0, bj = 0, bk = 0;
    if (tid < 192) {
      bg = tid >> 6; bj = (tid >> 2) & 15; bk = (tid & 3) << 2;
      bq = *(const float4*)&wsrc[(size_t)(bg * H_ + j0 + bj) * H_ + k0 + bk];
    }
    __syncthreads();
    As[ak+0][am]=a4.x; As[ak+1][am]=a4.y; As[ak+2][am]=a4.z; As[ak+3][am]=a4.w;
    if (tid < 192) {
      Bs[bg][bk+0][bj]=bq.x; Bs[bg][bk+1][bj]=bq.y; Bs[bg][bk+2][bj]=bq.z; Bs[bg][bk+3][bj]=bq.w;
    }
    __syncthreads();
#pragma unroll
    for (int k = 0; k < 16; k++) {
      const float a = As[k][m_row];
      const float4 br  = *(const float4*)&Bs[0][k][nl];
      const float4 bz  = *(const float4*)&Bs[1][k][nl];
      const float4 bn4 = *(const float4*)&Bs[2][k][nl];
      fma4(accR, a, br); fma4(accZ, a, bz); fma4(accNH, a, bn4);
    }
  }
  const int s_eff = (d == 0) ? t : (S_ - 1 - t);
  const float* bihd = bih + d * 768;
  const float* bhhd = bhh + d * 768;
  const float* gxr  = gx + ((size_t)m_row * S_ + s_eff) * 1536 + d * 768 + j0 + nl;
  const float4 g0 = *(const float4*)&gxr[0];
  const float4 g1 = *(const float4*)&gxr[256];
  const float4 g2 = *(const float4*)&gxr[512];
  const float4 hp = *(const float4*)&hbase[(size_t)m_row * H_ + j0 + nl];
  const float g0a[4]={g0.x,g0.y,g0.z,g0.w}, g1a[4]={g1.x,g1.y,g1.z,g1.w};
  const float g2a[4]={g2.x,g2.y,g2.z,g2.w}, hpa[4]={hp.x,hp.y,hp.z,hp.w};
  float o[4];
  float* hout = hnxt + (size_t)d * R_ * H_;
#pragma unroll
  for (int ji = 0; ji < 4; ji++) {
    const int j = j0 + nl + ji;
    const float r = sigmoidf_(g0a[ji] + bihd[j]       + accR[ji] + bhhd[j]);
    const float z = sigmoidf_(g1a[ji] + bihd[256 + j] + accZ[ji] + bhhd[256 + j]);
    const float n = tanhf   (g2a[ji] + bihd[512 + j] + r * (accNH[ji] + bhhd[512 + j]));
    o[ji] = (1.0f - z) * n + z * hpa[ji];
  }
  *(float4*)&hout[(size_t)m_row * H_ + j0 + nl] = make_float4(o[0],o[1],o[2],o[3]);
}

// ---------------------------------------------------------------------------
// Generic C[M,N] = A[M,K] @ B[N,K]^T  (BM=32, BN=64, KC=16; K may be ragged)
// ---------------------------------------------------------------------------
__global__ __launch_bounds__(256) void gemm_nt(
    const float* __restrict__ A, const float* __restrict__ B, float* __restrict__ C,
    int M, int N, int K)
{
  const int m0 = blockIdx.x * 32;
  const int n0 = blockIdx.y * 64;
  const int tid = threadIdx.x;
  __shared__ float As[16][36];
  __shared__ float Bs[16][68];
  float acc[2][4] = {{0}};
  const int mloc = (tid >> 4) << 1;
  const int nloc = (tid & 15) << 2;
  const int am = tid >> 3, ak = (tid & 7) << 1;
  const int bn = tid >> 2, bk = (tid & 3) << 2;
  for (int k0 = 0; k0 < K; k0 += 16) {
    float a0 = 0.0f, a1 = 0.0f;
    if (k0 + ak < K) { a0 = A[(size_t)(m0+am)*K + k0+ak]; a1 = A[(size_t)(m0+am)*K + k0+ak+1]; }
    float4 b4 = make_float4(0,0,0,0);
    if (k0 + bk < K) b4 = *(const float4*)&B[(size_t)(n0+bn)*K + k0+bk];
    __syncthreads();
    As[ak][am] = a0; As[ak+1][am] = a1;
    Bs[bk+0][bn]=b4.x; Bs[bk+1][bn]=b4.y; Bs[bk+2][bn]=b4.z; Bs[bk+3][bn]=b4.w;
    __syncthreads();
#pragma unroll
    for (int k = 0; k < 16; k++) {
      const float a0i = As[k][mloc], a1i = As[k][mloc+1];
      const float4 bb = *(const float4*)&Bs[k][nloc];
      fma4(acc[0], a0i, bb); fma4(acc[1], a1i, bb);
    }
  }
#pragma unroll
  for (int mi = 0; mi < 2; mi++)
    *(float4*)&C[(size_t)(m0+mloc+mi)*N + n0+nloc] =
        make_float4(acc[mi][0],acc[mi][1],acc[mi][2],acc[mi][3]);
}

// ---------------------------------------------------------------------------
// Review-level GRU: persistent, 2 blocks (one per direction), 768 threads,
// whh held packed-bf16 in VGPRs (one gate row per thread), 64 steps internal.
// ---------------------------------------------------------------------------
__global__ __launch_bounds__(768, 3) void revgru_k(
    const float* __restrict__ gx, const float* __restrict__ whh,
    const float* __restrict__ bih, const float* __restrict__ bhh,
    float* __restrict__ doc)
{
  const int d   = blockIdx.x;
  const int row = threadIdx.x;          // 0..767 gate row
  __shared__ float hb[2][H_];
  __shared__ float gh[768];

  unsigned wp[128];
  const float* wr = whh + ((size_t)d * 768 + row) * H_;
#pragma unroll
  for (int i = 0; i < 128; i++) {
    unsigned u0 = __float_as_uint(wr[2*i]);
    unsigned u1 = __float_as_uint(wr[2*i+1]);
    u0 = (u0 + 0x7fffu + ((u0 >> 16) & 1u)) >> 16;          // bf16 RTNE, low half
    u1 = (u1 + 0x7fffu + ((u1 >> 16) & 1u)) & 0xffff0000u;  // bf16 RTNE, high half
    wp[i] = u0 | u1;
  }
  const float bhh_r = bhh[(size_t)d * 768 + row];
  float bi0 = 0.f, bi1 = 0.f, bi2 = 0.f;
  if (row < H_) {
    bi0 = bih[d*768 + row];
    bi1 = bih[d*768 + 256 + row];
    bi2 = bih[d*768 + 512 + row];
    hb[0][row] = 0.0f;
  }
  __syncthreads();

  for (int t = 0; t < R_; t++) {
    const int cur = t & 1;
    float acc = bhh_r;
    const float4* h4p = (const float4*)hb[cur];
#pragma unroll
    for (int kk = 0; kk < 64; kk++) {
      const float4 h4 = h4p[kk];
      const unsigned w0 = wp[2*kk], w1 = wp[2*kk+1];
      acc += __uint_as_float(w0 << 16)          * h4.x;
      acc += __uint_as_float(w0 & 0xffff0000u)  * h4.y;
      acc += __uint_as_float(w1 << 16)          * h4.z;
      acc += __uint_as_float(w1 & 0xffff0000u)  * h4.w;
    }
    gh[row] = acc;
    __syncthreads();
    if (row < H_) {
      const int teff = (d == 0) ? t : (R_ - 1 - t);
      const float* gxr = gx + (size_t)teff * 1536 + d * 768;
      const float r = sigmoidf_(gxr[row]       + bi0 + gh[row]);
      const float z = sigmoidf_(gxr[256 + row] + bi1 + gh[256 + row]);
      const float n = tanhf   (gxr[512 + row] + bi2 + r * gh[512 + row]);
      const float hn = (1.0f - z) * n + z * hb[cur][row];
      hb[1 - cur][row] = hn;
      if (t == R_ - 1) doc[d * H_ + row] = hn;
    }
    __syncthreads();
  }
}

// ---------------------------------------------------------------------------
// Small glue kernels
// ---------------------------------------------------------------------------
__global__ void add2k(const float4* __restrict__ a, const float4* __restrict__ b,
                      float4* __restrict__ c)
{
  const int i = blockIdx.x * blockDim.x + threadIdx.x;
  const float4 x = a[i], y = b[i];
  c[i] = make_float4(x.x+y.x, x.y+y.y, x.z+y.z, x.w+y.w);
}

__global__ void pbatch_k(const float* __restrict__ hs, const float* __restrict__ uf,
                         const float* __restrict__ ufw, float* __restrict__ pb)
{
  const int r = blockIdx.x, tid = threadIdx.x;
  __shared__ float nrm;
  if (tid == 0) {
    float s = 0.f;
    for (int i = 0; i < UF_; i++) { const float v = uf[r*UF_ + i]; s += v*v; }
    nrm = fmaxf(sqrtf(s), 1e-12f);
  }
  __syncthreads();
  if (tid < H_)  pb[r*276 + tid] = hs[r*H_ + tid] + hs[(size_t)R_*H_ + r*H_ + tid];
  if (tid < UF_) pb[r*276 + H_ + tid] = uf[r*UF_ + tid] / nrm * ufw[tid];
}

__global__ void rstars_k(const float* __restrict__ pb,
                         const float* __restrict__ w1, const float* __restrict__ b1,
                         const float* __restrict__ w2, const float* __restrict__ b2,
                         float* __restrict__ out)
{
  const int r = blockIdx.x, tid = threadIdx.x;   // 128 threads
  __shared__ float ps[276];
  __shared__ float s1[128];
  for (int i = tid; i < 276; i += 128) ps[i] = pb[r*276 + i];
  __syncthreads();
  float a = b1[tid];
  for (int k = 0; k < 276; k++) a += ps[k] * w1[tid*276 + k];
  s1[tid] = seluf_(a);
  __syncthreads();
  if (tid == 0) {
    float s = b2[0];
    for (int k = 0; k < 128; k++) s += s1[k] * w2[k];
    out[9 + r] = s;
  }
}

__global__ void pstars_k(const float* __restrict__ doc2,
                         const float* __restrict__ w1, const float* __restrict__ b1,
                         const float* __restrict__ w2, const float* __restrict__ b2,
                         float* __restrict__ out)
{
  const int tid = threadIdx.x;   // 128 threads
  __shared__ float dc[256];
  __shared__ float s1[128];
  dc[tid]       = doc2[tid]       + doc2[256 + tid];
  dc[128 + tid] = doc2[128 + tid] + doc2[384 + tid];
  __syncthreads();
  float a = b1[tid];
  for (int k = 0; k < 256; k++) a += dc[k] * w1[tid*256 + k];
  s1[tid] = seluf_(a);
  __syncthreads();
  if (tid < 9) {
    float s = b2[tid];
    for (int k = 0; k < 128; k++) s += s1[k] * w2[tid*128 + k];
    out[tid] = s;
  }
}

// ---------------------------------------------------------------------------
extern "C" void kernel_launch(void* const* d_in, const int* in_sizes, int n_in,
                              void* d_out, int out_size, void* d_ws, size_t ws_size,
                              hipStream_t stream)
{
  const int*   toks   = (const int*)  d_in[0];
  // d_in[1]=sent_lengths, d_in[2]=sent_counts -- unused by the reference
  const float* uf     = (const float*)d_in[3];
  const float* embed  = (const float*)d_in[4];
  const float* wg_wih = (const float*)d_in[5];
  const float* wg_whh = (const float*)d_in[6];
  const float* wg_bih = (const float*)d_in[7];
  const float* wg_bhh = (const float*)d_in[8];
  const float* sg_wih = (const float*)d_in[9];
  const float* sg_whh = (const float*)d_in[10];
  const float* sg_bih = (const float*)d_in[11];
  const float* sg_bhh = (const float*)d_in[12];
  const float* rg_wih = (const float*)d_in[13];
  const float* rg_whh = (const float*)d_in[14];
  const float* rg_bih = (const float*)d_in[15];
  const float* rg_bhh = (const float*)d_in[16];
  const float* rfc_w1 = (const float*)d_in[17];
  const float* rfc_b1 = (const float*)d_in[18];
  const float* rfc_w2 = (const float*)d_in[19];
  const float* rfc_b2 = (const float*)d_in[20];
  const float* pfc_w1 = (const float*)d_in[21];
  const float* pfc_b1 = (const float*)d_in[22];
  const float* pfc_w2 = (const float*)d_in[23];
  const float* pfc_b2 = (const float*)d_in[24];
  const float* uf_w   = (const float*)d_in[25];
  float* out = (float*)d_out;
  float* ws  = (float*)d_ws;
  (void)in_sizes; (void)n_in; (void)out_size; (void)ws_size;

  // workspace layout (floats); total ~5.95M floats = ~23.8 MB
  const size_t SZ_HWBUF = (size_t)2 * 2048 * H_;          // one ping-pong buf (2 dirs)
  const size_t OFF_SENT = 2 * SZ_HWBUF;                   // 2,097,152
  const size_t OFF_GXS  = OFF_SENT + (size_t)2048 * H_;   // + 524,288
  const size_t OFF_HS   = OFF_GXS  + (size_t)2048 * 1536; // + 3,145,728
  const size_t SZ_HSBUF = (size_t)2 * R_ * H_;
  const size_t OFF_PB   = OFF_HS  + 2 * SZ_HSBUF;
  const size_t OFF_GXR  = OFF_PB  + (size_t)R_ * 276;
  const size_t OFF_DOC  = OFF_GXR + (size_t)R_ * 1536;

  float* hw   = ws;
  float* sent = ws + OFF_SENT;
  float* gxs  = ws + OFF_GXS;
  float* hs   = ws + OFF_HS;
  float* pb   = ws + OFF_PB;
  float* gxr  = ws + OFF_GXR;
  float* doc  = ws + OFF_DOC;

  // zero initial hidden states (ws is re-poisoned before every call)
  hipMemsetAsync(hw, 0, SZ_HWBUF * sizeof(float), stream);
  hipMemsetAsync(hs, 0, SZ_HSBUF * sizeof(float), stream);

  // word-level bi-GRU: 64 fused steps (final h lands in buf 0)
  for (int t = 0; t < W_; t++) {
    float* hc = hw + (size_t)( t      & 1) * SZ_HWBUF;
    float* hn = hw + (size_t)((t + 1) & 1) * SZ_HWBUF;
    word_step<<<dim3(64, 4, 2), 256, 0, stream>>>(t, toks, embed,
        wg_wih, wg_whh, wg_bih, wg_bhh, hc, hn);
  }
  // sent[b][u] = h_fwd + h_bwd
  add2k<<<512, 256, 0, stream>>>((const float4*)hw,
      (const float4*)(hw + (size_t)2048 * H_), (float4*)sent);

  // sentence-level: gx precompute then 32 steps
  gemm_nt<<<dim3(2048/32, 1536/64), 256, 0, stream>>>(sent, sg_wih, gxs, 2048, 1536, 256);
  for (int t = 0; t < S_; t++) {
    float* hc = hs + (size_t)( t      & 1) * SZ_HSBUF;
    float* hn = hs + (size_t)((t + 1) & 1) * SZ_HSBUF;
    sent_step<<<dim3(1, 16, 2), 256, 0, stream>>>(t, gxs, sg_whh, sg_bih, sg_bhh, hc, hn);
  }

  // p_batch + r_stars
  pbatch_k<<<R_, 256, 0, stream>>>(hs, uf, uf_w, pb);
  rstars_k<<<R_, 128, 0, stream>>>(pb, rfc_w1, rfc_b1, rfc_w2, rfc_b2, out);

  // review-level: gx precompute (K=276), persistent bi-GRU, p_stars
  gemm_nt<<<dim3(R_/32, 1536/64), 256, 0, stream>>>(pb, rg_wih, gxr, R_, 1536, 276);
  revgru_k<<<2, 768, 0, stream>>>(gxr, rg_whh, rg_bih, rg_bhh, doc);
  pstars_k<<<1, 128, 0, stream>>>(doc, pfc_w1, pfc_b1, pfc_w2, pfc_b2, out);
}

// Round 2
// 2401.712 us; speedup vs baseline: 2.3299x; 2.3299x over previous
//
#include <hip/hip_runtime.h>
#include <math.h>

#define R_ 64
#define S_ 32
#define W_ 64
#define H_ 256
#define UF_ 20

typedef short bf16x8 __attribute__((ext_vector_type(8)));
typedef float f32x4  __attribute__((ext_vector_type(4)));

#define MFMA(a,b,c) __builtin_amdgcn_mfma_f32_16x16x32_bf16((a),(b),(c),0,0,0)

__device__ __forceinline__ float sigf(float x){ return 1.0f/(1.0f+__expf(-x)); }
__device__ __forceinline__ float tanhf_(float x){ float e=__expf(2.0f*x); return 1.0f-2.0f/(e+1.0f); }
__device__ __forceinline__ float seluf_(float x){
  const float sc=1.0507009873554805f, al=1.6732632423543772f;
  return x>0.0f ? sc*x : sc*al*(expf(x)-1.0f);
}
__device__ __forceinline__ short tobf(float f){
  unsigned u=__float_as_uint(f); u += 0x7fffu + ((u>>16)&1u); return (short)(u>>16);
}
__device__ __forceinline__ void fma4(float (&acc)[4], float a, const float4 b){
  acc[0]+=a*b.x; acc[1]+=a*b.y; acc[2]+=a*b.z; acc[3]+=a*b.w;
}

// ---------------------------------------------------------------------------
// Weight swizzle preps: B-fragment order for mfma_f32_16x16x32_bf16.
// B-frag: lane l holds B[k = (l>>4)*8 + j][n = l&15], j=0..7 (16B contiguous).
// Word layout Bw[d][ntc 64][kt 16][lane 64][8]:
//   ntc 0..15 r, 16..31 z, 32..47 n_x (kt 0..7, wih), 48..63 n_h (kt 8..15, whh)
//   r/z: kt 0..7 from wih, kt 8..15 from whh.
// ---------------------------------------------------------------------------
__global__ void prep_word_w(const float* __restrict__ wih, const float* __restrict__ whh,
                            short* __restrict__ Bw)
{
  int idx = blockIdx.x*256 + threadIdx.x;            // 2*64*16*64 = 131072
  int lane = idx & 63, kt = (idx>>6)&15, ntc = (idx>>10)&63, d = (idx>>16)&1;
  bool is_nx = (ntc>=32 && ntc<48), is_nh = (ntc>=48);
  if (is_nx && kt>=8) return;
  if (is_nh && kt<8)  return;
  int c = lane&15, q = lane>>4;
  int n;
  if (ntc<16)       n = ntc*16 + c;
  else if (ntc<32)  n = 256 + (ntc-16)*16 + c;
  else if (is_nx)   n = 512 + (ntc-32)*16 + c;
  else              n = 512 + (ntc-48)*16 + c;
  bool use_h = (!is_nx) && (kt>=8);
  int ktl = use_h ? (kt-8) : kt;
  const float* W = (use_h ? whh : wih) + (size_t)d*768*256;
  int k = ktl*32 + q*8;
  short* dst = Bw + ((((size_t)d*64 + ntc)*16 + kt)*64 + lane)*8;
#pragma unroll
  for (int j=0;j<8;j++) dst[j] = tobf(W[(size_t)n*256 + k + j]);
}

// Bs/Br layout [d][ntc 48][kt 8][lane][8]: ntc 0..15 r, 16..31 z, 32..47 n_h (all whh)
__global__ void prep_rnn_w(const float* __restrict__ whh, short* __restrict__ Bs)
{
  int idx = blockIdx.x*256 + threadIdx.x;            // 2*64*8*64 = 65536 (48 used)
  int lane = idx & 63, kt = (idx>>6)&7, ntc = (idx>>9)&63, d = (idx>>15)&1;
  if (ntc >= 48) return;
  int c = lane&15, q = lane>>4;
  int n;
  if (ntc<16)      n = ntc*16 + c;
  else if (ntc<32) n = 256 + (ntc-16)*16 + c;
  else             n = 512 + (ntc-32)*16 + c;
  const float* W = whh + (size_t)d*768*256;
  int k = kt*32 + q*8;
  short* dst = Bs + ((((size_t)d*48 + ntc)*8 + kt)*64 + lane)*8;
#pragma unroll
  for (int j=0;j<8;j++) dst[j] = tobf(W[(size_t)n*256 + k + j]);
}

// ---------------------------------------------------------------------------
// Persistent word-level bi-GRU. Grid 128 = 64 sentence-groups x 2 dirs.
// Block: 512 thr (8 waves). Per step: M=32, N=768(4 gate groups), K=512 bf16 MFMA.
// h fp32 lives in registers (lane-local epilogue); bf16 h copy in LDS for A-frags.
// ---------------------------------------------------------------------------
__global__ __launch_bounds__(512, 2) void word_gru(
    const int* __restrict__ toks, const float* __restrict__ embed,
    const short* __restrict__ Bw,
    const float* __restrict__ bih, const float* __restrict__ bhh,
    float* __restrict__ hfin)
{
  const int d = blockIdx.x & 1;
  const int g = blockIdx.x >> 1;
  const int tid = threadIdx.x;
  const int w = tid >> 6, l = tid & 63;
  const int c = l & 15, q = l >> 4;

  __shared__ short hbf[32][264];        // pitch 264 shorts (528B, 16B-mult)
  __shared__ short ebuf[2][32][264];
  __shared__ int   tokL[32*64];

  for (int i = tid; i < 32*64; i += 512) {
    int s = i >> 6, wd = i & 63;
    tokL[i] = toks[(size_t)(g*32 + s)*64 + wd];
  }
  for (int i = tid; i < 32*264; i += 512) ((short*)hbf)[i] = 0;

  float bR[2], bZ[2], bNX[2], bNH[2];
#pragma unroll
  for (int jt = 0; jt < 2; jt++) {
    int j = 32*w + jt*16 + c;
    bR[jt]  = bih[d*768 + j]       + bhh[d*768 + j];
    bZ[jt]  = bih[d*768 + 256 + j] + bhh[d*768 + 256 + j];
    bNX[jt] = bih[d*768 + 512 + j];
    bNH[jt] = bhh[d*768 + 512 + j];
  }
  float hst[2][2][4];
#pragma unroll
  for (int a=0;a<2;a++)
#pragma unroll
  for (int b=0;b<2;b++)
#pragma unroll
  for (int r=0;r<4;r++) hst[a][b][r] = 0.0f;

  __syncthreads();

  const int erow = tid >> 4, ecol = (tid & 15) * 16;
  float4 ef[4];
  { // prefetch emb for t=0
    int tx = (d == 0) ? 0 : 63;
    const float* src = embed + (size_t)tokL[erow*64 + tx]*256 + ecol;
    ef[0]=*(const float4*)(src); ef[1]=*(const float4*)(src+4);
    ef[2]=*(const float4*)(src+8); ef[3]=*(const float4*)(src+12);
  }

  const size_t bbase = (size_t)d * 64 * 16 * 64 * 8;

  for (int t = 0; t < 64; t++) {
    const int cur = t & 1;
    { // stage prefetched embedding row -> ebuf[cur] (bf16)
      unsigned* dst = (unsigned*)&ebuf[cur][erow][ecol];
      const float* e = (const float*)ef;
#pragma unroll
      for (int i = 0; i < 8; i++) {
        unsigned lo = (unsigned short)tobf(e[2*i]);
        unsigned hi = (unsigned short)tobf(e[2*i+1]);
        dst[i] = lo | (hi << 16);
      }
    }
    __syncthreads();   // ebuf ready; prev epilogue's hbf writes visible

    if (t < 63) { // prefetch emb for t+1
      int tx = (d == 0) ? (t+1) : (62 - t);
      const float* src = embed + (size_t)tokL[erow*64 + tx]*256 + ecol;
      ef[0]=*(const float4*)(src); ef[1]=*(const float4*)(src+4);
      ef[2]=*(const float4*)(src+8); ef[3]=*(const float4*)(src+12);
    }

    f32x4 accR[2][2], accZ[2][2], accNX[2][2], accNH[2][2];
#pragma unroll
    for (int a=0;a<2;a++)
#pragma unroll
    for (int b=0;b<2;b++) { accR[a][b]=(f32x4)0.f; accZ[a][b]=(f32x4)0.f;
                            accNX[a][b]=(f32x4)0.f; accNH[a][b]=(f32x4)0.f; }

    const short* asrcE = &ebuf[cur][0][0];
    const short* asrcH = &hbf[0][0];
#pragma unroll
    for (int kt = 0; kt < 16; kt++) {
      const bool xph = (kt < 8);
      const short* asrc = xph ? asrcE : asrcH;
      const int ko = (kt & 7) * 32 + q * 8;
      bf16x8 a0 = *(const bf16x8*)&asrc[(0  + c) * 264 + ko];
      bf16x8 a1 = *(const bf16x8*)&asrc[(16 + c) * 264 + ko];
      const int n4 = (xph ? 32 : 48) + 2*w;
      const short* bp = Bw + bbase;
      bf16x8 bR0 = *(const bf16x8*)&bp[(((2*w  )*16 + kt)*64 + l)*8];
      bf16x8 bR1 = *(const bf16x8*)&bp[(((2*w+1)*16 + kt)*64 + l)*8];
      bf16x8 bZ0 = *(const bf16x8*)&bp[(((16+2*w)*16 + kt)*64 + l)*8];
      bf16x8 bZ1 = *(const bf16x8*)&bp[(((17+2*w)*16 + kt)*64 + l)*8];
      bf16x8 bN0 = *(const bf16x8*)&bp[(((n4   )*16 + kt)*64 + l)*8];
      bf16x8 bN1 = *(const bf16x8*)&bp[(((n4+1 )*16 + kt)*64 + l)*8];
      accR[0][0]=MFMA(a0,bR0,accR[0][0]); accR[0][1]=MFMA(a1,bR0,accR[0][1]);
      accR[1][0]=MFMA(a0,bR1,accR[1][0]); accR[1][1]=MFMA(a1,bR1,accR[1][1]);
      accZ[0][0]=MFMA(a0,bZ0,accZ[0][0]); accZ[0][1]=MFMA(a1,bZ0,accZ[0][1]);
      accZ[1][0]=MFMA(a0,bZ1,accZ[1][0]); accZ[1][1]=MFMA(a1,bZ1,accZ[1][1]);
      if (xph) {
        accNX[0][0]=MFMA(a0,bN0,accNX[0][0]); accNX[0][1]=MFMA(a1,bN0,accNX[0][1]);
        accNX[1][0]=MFMA(a0,bN1,accNX[1][0]); accNX[1][1]=MFMA(a1,bN1,accNX[1][1]);
      } else {
        accNH[0][0]=MFMA(a0,bN0,accNH[0][0]); accNH[0][1]=MFMA(a1,bN0,accNH[0][1]);
        accNH[1][0]=MFMA(a0,bN1,accNH[1][0]); accNH[1][1]=MFMA(a1,bN1,accNH[1][1]);
      }
    }
    __syncthreads();   // all hbf reads done

    // lane-local epilogue: r,z,nx,nh for (m,j) all live in this lane
#pragma unroll
    for (int mt = 0; mt < 2; mt++)
#pragma unroll
    for (int jt = 0; jt < 2; jt++)
#pragma unroll
    for (int rg = 0; rg < 4; rg++) {
      const float r = sigf(accR[jt][mt][rg] + bR[jt]);
      const float z = sigf(accZ[jt][mt][rg] + bZ[jt]);
      const float n = tanhf_(accNX[jt][mt][rg] + bNX[jt] + r*(accNH[jt][mt][rg] + bNH[jt]));
      float h = hst[mt][jt][rg];
      h = (1.0f - z)*n + z*h;
      hst[mt][jt][rg] = h;
      const int m = mt*16 + q*4 + rg;
      const int j = 32*w + jt*16 + c;
      hbf[m][j] = tobf(h);
    }
  }
  __syncthreads();
#pragma unroll
  for (int mt = 0; mt < 2; mt++)
#pragma unroll
  for (int jt = 0; jt < 2; jt++)
#pragma unroll
  for (int rg = 0; rg < 4; rg++) {
    const int m = mt*16 + q*4 + rg;
    const int j = 32*w + jt*16 + c;
    hfin[((size_t)d*2048 + g*32 + m)*256 + j] = hst[mt][jt][rg];
  }
}

// ---------------------------------------------------------------------------
// Persistent sentence-level bi-GRU. Grid 8 = 4 review-groups x 2 dirs.
// Per step: M=16 reviews, N=768 (r,z,n_h), K=256 (h only); gx precomputed fp32.
// ---------------------------------------------------------------------------
__global__ __launch_bounds__(512, 2) void sent_gru(
    const float* __restrict__ gx, const short* __restrict__ Bs,
    const float* __restrict__ bih, const float* __restrict__ bhh,
    float* __restrict__ hs)
{
  const int d = blockIdx.x & 1;
  const int g = blockIdx.x >> 1;     // reviews g*16 .. g*16+15
  const int tid = threadIdx.x;
  const int w = tid >> 6, l = tid & 63;
  const int c = l & 15, q = l >> 4;

  __shared__ short hbf[16][264];
  for (int i = tid; i < 16*264; i += 512) ((short*)hbf)[i] = 0;

  float bR[2], bZ[2], bNX[2], bNH[2];
#pragma unroll
  for (int jt = 0; jt < 2; jt++) {
    int j = 32*w + jt*16 + c;
    bR[jt]  = bih[d*768 + j]       + bhh[d*768 + j];
    bZ[jt]  = bih[d*768 + 256 + j] + bhh[d*768 + 256 + j];
    bNX[jt] = bih[d*768 + 512 + j];
    bNH[jt] = bhh[d*768 + 512 + j];
  }
  float hst[2][4];
#pragma unroll
  for (int a=0;a<2;a++)
#pragma unroll
  for (int r=0;r<4;r++) hst[a][r] = 0.0f;
  __syncthreads();

  const size_t bbase = (size_t)d * 48 * 8 * 64 * 8;

  for (int t = 0; t < 32; t++) {
    const int s_eff = (d == 0) ? t : (31 - t);
    // prefetch gx (latency hidden behind mfma)
    float gr[2][4], gz[2][4], gn[2][4];
#pragma unroll
    for (int jt = 0; jt < 2; jt++)
#pragma unroll
    for (int rg = 0; rg < 4; rg++) {
      const int m = q*4 + rg;
      const int j = 32*w + jt*16 + c;
      const size_t row = ((size_t)(g*16 + m)*32 + s_eff)*1536 + d*768;
      gr[jt][rg] = gx[row + j];
      gz[jt][rg] = gx[row + 256 + j];
      gn[jt][rg] = gx[row + 512 + j];
    }

    f32x4 accR[2], accZ[2], accNH[2];
#pragma unroll
    for (int a=0;a<2;a++) { accR[a]=(f32x4)0.f; accZ[a]=(f32x4)0.f; accNH[a]=(f32x4)0.f; }

#pragma unroll
    for (int kt = 0; kt < 8; kt++) {
      const int ko = kt * 32 + q * 8;
      bf16x8 a0 = *(const bf16x8*)&hbf[c][ko];
      const short* bp = Bs + bbase;
      bf16x8 bR0 = *(const bf16x8*)&bp[(((2*w   )*8 + kt)*64 + l)*8];
      bf16x8 bR1 = *(const bf16x8*)&bp[(((2*w+1 )*8 + kt)*64 + l)*8];
      bf16x8 bZ0 = *(const bf16x8*)&bp[(((16+2*w)*8 + kt)*64 + l)*8];
      bf16x8 bZ1 = *(const bf16x8*)&bp[(((17+2*w)*8 + kt)*64 + l)*8];
      bf16x8 bN0 = *(const bf16x8*)&bp[(((32+2*w)*8 + kt)*64 + l)*8];
      bf16x8 bN1 = *(const bf16x8*)&bp[(((33+2*w)*8 + kt)*64 + l)*8];
      accR[0]=MFMA(a0,bR0,accR[0]);  accR[1]=MFMA(a0,bR1,accR[1]);
      accZ[0]=MFMA(a0,bZ0,accZ[0]);  accZ[1]=MFMA(a0,bZ1,accZ[1]);
      accNH[0]=MFMA(a0,bN0,accNH[0]); accNH[1]=MFMA(a0,bN1,accNH[1]);
    }
    __syncthreads();
#pragma unroll
    for (int jt = 0; jt < 2; jt++)
#pragma unroll
    for (int rg = 0; rg < 4; rg++) {
      const float r = sigf(gr[jt][rg] + bR[jt] + accR[jt][rg]);
      const float z = sigf(gz[jt][rg] + bZ[jt] + accZ[jt][rg]);
      const float n = tanhf_(gn[jt][rg] + bNX[jt] + r*(accNH[jt][rg] + bNH[jt]));
      float h = hst[jt][rg];
      h = (1.0f - z)*n + z*h;
      hst[jt][rg] = h;
      const int m = q*4 + rg;
      const int j = 32*w + jt*16 + c;
      hbf[m][j] = tobf(h);
    }
    __syncthreads();
  }
#pragma unroll
  for (int jt = 0; jt < 2; jt++)
#pragma unroll
  for (int rg = 0; rg < 4; rg++) {
    const int m = q*4 + rg;
    const int j = 32*w + jt*16 + c;
    hs[((size_t)d*64 + g*16 + m)*256 + j] = hst[jt][rg];
  }
}

// ---------------------------------------------------------------------------
// Review-level bi-GRU, batch 1. Same M=16 structure; all 16 rows compute the
// same review (broadcast gx row) -- only m==0 writes doc. Grid 2 (dirs).
// ---------------------------------------------------------------------------
__global__ __launch_bounds__(512, 2) void rev_gru(
    const float* __restrict__ gx, const short* __restrict__ Br,
    const float* __restrict__ bih, const float* __restrict__ bhh,
    float* __restrict__ doc)
{
  const int d = blockIdx.x;
  const int tid = threadIdx.x;
  const int w = tid >> 6, l = tid & 63;
  const int c = l & 15, q = l >> 4;

  __shared__ short hbf[16][264];
  for (int i = tid; i < 16*264; i += 512) ((short*)hbf)[i] = 0;

  float bR[2], bZ[2], bNX[2], bNH[2];
#pragma unroll
  for (int jt = 0; jt < 2; jt++) {
    int j = 32*w + jt*16 + c;
    bR[jt]  = bih[d*768 + j]       + bhh[d*768 + j];
    bZ[jt]  = bih[d*768 + 256 + j] + bhh[d*768 + 256 + j];
    bNX[jt] = bih[d*768 + 512 + j];
    bNH[jt] = bhh[d*768 + 512 + j];
  }
  float hst[2][4];
#pragma unroll
  for (int a=0;a<2;a++)
#pragma unroll
  for (int r=0;r<4;r++) hst[a][r] = 0.0f;
  __syncthreads();

  const size_t bbase = (size_t)d * 48 * 8 * 64 * 8;

  for (int t = 0; t < 64; t++) {
    const int teff = (d == 0) ? t : (63 - t);
    float gr[2], gz[2], gn[2];
#pragma unroll
    for (int jt = 0; jt < 2; jt++) {
      const int j = 32*w + jt*16 + c;
      const size_t row = (size_t)teff*1536 + d*768;
      gr[jt] = gx[row + j]; gz[jt] = gx[row + 256 + j]; gn[jt] = gx[row + 512 + j];
    }
    f32x4 accR[2], accZ[2], accNH[2];
#pragma unroll
    for (int a=0;a<2;a++) { accR[a]=(f32x4)0.f; accZ[a]=(f32x4)0.f; accNH[a]=(f32x4)0.f; }
#pragma unroll
    for (int kt = 0; kt < 8; kt++) {
      const int ko = kt * 32 + q * 8;
      bf16x8 a0 = *(const bf16x8*)&hbf[c][ko];
      const short* bp = Br + bbase;
      bf16x8 bR0 = *(const bf16x8*)&bp[(((2*w   )*8 + kt)*64 + l)*8];
      bf16x8 bR1 = *(const bf16x8*)&bp[(((2*w+1 )*8 + kt)*64 + l)*8];
      bf16x8 bZ0 = *(const bf16x8*)&bp[(((16+2*w)*8 + kt)*64 + l)*8];
      bf16x8 bZ1 = *(const bf16x8*)&bp[(((17+2*w)*8 + kt)*64 + l)*8];
      bf16x8 bN0 = *(const bf16x8*)&bp[(((32+2*w)*8 + kt)*64 + l)*8];
      bf16x8 bN1 = *(const bf16x8*)&bp[(((33+2*w)*8 + kt)*64 + l)*8];
      accR[0]=MFMA(a0,bR0,accR[0]);  accR[1]=MFMA(a0,bR1,accR[1]);
      accZ[0]=MFMA(a0,bZ0,accZ[0]);  accZ[1]=MFMA(a0,bZ1,accZ[1]);
      accNH[0]=MFMA(a0,bN0,accNH[0]); accNH[1]=MFMA(a0,bN1,accNH[1]);
    }
    __syncthreads();
#pragma unroll
    for (int jt = 0; jt < 2; jt++)
#pragma unroll
    for (int rg = 0; rg < 4; rg++) {
      const float r = sigf(gr[jt] + bR[jt] + accR[jt][rg]);
      const float z = sigf(gz[jt] + bZ[jt] + accZ[jt][rg]);
      const float n = tanhf_(gn[jt] + bNX[jt] + r*(accNH[jt][rg] + bNH[jt]));
      float h = hst[jt][rg];
      h = (1.0f - z)*n + z*h;
      hst[jt][rg] = h;
      const int m = q*4 + rg;
      const int j = 32*w + jt*16 + c;
      hbf[m][j] = tobf(h);
    }
    __syncthreads();
  }
  if (q == 0) {
#pragma unroll
    for (int jt = 0; jt < 2; jt++) {
      const int j = 32*w + jt*16 + c;
      doc[d*256 + j] = hst[jt][0];
    }
  }
}

// ---------------------------------------------------------------------------
// Generic C[M,N] = A[M,K] @ B[N,K]^T  (fp32, BM=32, BN=64, KC=16)
// ---------------------------------------------------------------------------
__global__ __launch_bounds__(256) void gemm_nt(
    const float* __restrict__ A, const float* __restrict__ B, float* __restrict__ C,
    int M, int N, int K)
{
  const int m0 = blockIdx.x * 32;
  const int n0 = blockIdx.y * 64;
  const int tid = threadIdx.x;
  __shared__ float As[16][36];
  __shared__ float Bs[16][68];
  float acc[2][4] = {{0}};
  const int mloc = (tid >> 4) << 1;
  const int nloc = (tid & 15) << 2;
  const int am = tid >> 3, ak = (tid & 7) << 1;
  const int bn = tid >> 2, bk = (tid & 3) << 2;
  for (int k0 = 0; k0 < K; k0 += 16) {
    float a0 = 0.0f, a1 = 0.0f;
    if (k0 + ak < K) { a0 = A[(size_t)(m0+am)*K + k0+ak]; a1 = A[(size_t)(m0+am)*K + k0+ak+1]; }
    float4 b4 = make_float4(0,0,0,0);
    if (k0 + bk < K) b4 = *(const float4*)&B[(size_t)(n0+bn)*K + k0+bk];
    __syncthreads();
    As[ak][am] = a0; As[ak+1][am] = a1;
    Bs[bk+0][bn]=b4.x; Bs[bk+1][bn]=b4.y; Bs[bk+2][bn]=b4.z; Bs[bk+3][bn]=b4.w;
    __syncthreads();
#pragma unroll
    for (int k = 0; k < 16; k++) {
      const float a0i = As[k][mloc], a1i = As[k][mloc+1];
      const float4 bb = *(const float4*)&Bs[k][nloc];
      fma4(acc[0], a0i, bb); fma4(acc[1], a1i, bb);
    }
  }
#pragma unroll
  for (int mi = 0; mi < 2; mi++)
    *(float4*)&C[(size_t)(m0+mloc+mi)*N + n0+nloc] =
        make_float4(acc[mi][0],acc[mi][1],acc[mi][2],acc[mi][3]);
}

// ---------------------------------------------------------------------------
// Small glue kernels
// ---------------------------------------------------------------------------
__global__ void add2k(const float4* __restrict__ a, const float4* __restrict__ b,
                      float4* __restrict__ c)
{
  const int i = blockIdx.x * blockDim.x + threadIdx.x;
  const float4 x = a[i], y = b[i];
  c[i] = make_float4(x.x+y.x, x.y+y.y, x.z+y.z, x.w+y.w);
}

__global__ void pbatch_k(const float* __restrict__ hs, const float* __restrict__ uf,
                         const float* __restrict__ ufw, float* __restrict__ pb)
{
  const int r = blockIdx.x, tid = threadIdx.x;
  __shared__ float nrm;
  if (tid == 0) {
    float s = 0.f;
    for (int i = 0; i < UF_; i++) { const float v = uf[r*UF_ + i]; s += v*v; }
    nrm = fmaxf(sqrtf(s), 1e-12f);
  }
  __syncthreads();
  if (tid < H_)  pb[r*276 + tid] = hs[r*H_ + tid] + hs[(size_t)R_*H_ + r*H_ + tid];
  if (tid < UF_) pb[r*276 + H_ + tid] = uf[r*UF_ + tid] / nrm * ufw[tid];
}

__global__ void rstars_k(const float* __restrict__ pb,
                         const float* __restrict__ w1, const float* __restrict__ b1,
                         const float* __restrict__ w2, const float* __restrict__ b2,
                         float* __restrict__ out)
{
  const int r = blockIdx.x, tid = threadIdx.x;   // 128 threads
  __shared__ float ps[276];
  __shared__ float s1[128];
  for (int i = tid; i < 276; i += 128) ps[i] = pb[r*276 + i];
  __syncthreads();
  float a = b1[tid];
  for (int k = 0; k < 276; k++) a += ps[k] * w1[tid*276 + k];
  s1[tid] = seluf_(a);
  __syncthreads();
  if (tid == 0) {
    float s = b2[0];
    for (int k = 0; k < 128; k++) s += s1[k] * w2[k];
    out[9 + r] = s;
  }
}

__global__ void pstars_k(const float* __restrict__ doc2,
                         const float* __restrict__ w1, const float* __restrict__ b1,
                         const float* __restrict__ w2, const float* __restrict__ b2,
                         float* __restrict__ out)
{
  const int tid = threadIdx.x;   // 128 threads
  __shared__ float dc[256];
  __shared__ float s1[128];
  dc[tid]       = doc2[tid]       + doc2[256 + tid];
  dc[128 + tid] = doc2[128 + tid] + doc2[384 + tid];
  __syncthreads();
  float a = b1[tid];
  for (int k = 0; k < 256; k++) a += dc[k] * w1[tid*256 + k];
  s1[tid] = seluf_(a);
  __syncthreads();
  if (tid < 9) {
    float s = b2[tid];
    for (int k = 0; k < 128; k++) s += s1[k] * w2[tid*128 + k];
    out[tid] = s;
  }
}

// ---------------------------------------------------------------------------
extern "C" void kernel_launch(void* const* d_in, const int* in_sizes, int n_in,
                              void* d_out, int out_size, void* d_ws, size_t ws_size,
                              hipStream_t stream)
{
  const int*   toks   = (const int*)  d_in[0];
  const float* uf     = (const float*)d_in[3];
  const float* embed  = (const float*)d_in[4];
  const float* wg_wih = (const float*)d_in[5];
  const float* wg_whh = (const float*)d_in[6];
  const float* wg_bih = (const float*)d_in[7];
  const float* wg_bhh = (const float*)d_in[8];
  const float* sg_wih = (const float*)d_in[9];
  const float* sg_whh = (const float*)d_in[10];
  const float* sg_bih = (const float*)d_in[11];
  const float* sg_bhh = (const float*)d_in[12];
  const float* rg_wih = (const float*)d_in[13];
  const float* rg_whh = (const float*)d_in[14];
  const float* rg_bih = (const float*)d_in[15];
  const float* rg_bhh = (const float*)d_in[16];
  const float* rfc_w1 = (const float*)d_in[17];
  const float* rfc_b1 = (const float*)d_in[18];
  const float* rfc_w2 = (const float*)d_in[19];
  const float* rfc_b2 = (const float*)d_in[20];
  const float* pfc_w1 = (const float*)d_in[21];
  const float* pfc_b1 = (const float*)d_in[22];
  const float* pfc_w2 = (const float*)d_in[23];
  const float* pfc_b2 = (const float*)d_in[24];
  const float* uf_w   = (const float*)d_in[25];
  float* out = (float*)d_out;
  float* ws  = (float*)d_ws;
  (void)in_sizes; (void)n_in; (void)out_size; (void)ws_size;

  // workspace layout (float offsets), total ~5.79M floats = 23.1 MB
  const size_t OFF_BW   = 0;                       // 524288 (as shorts: 1,048,576)
  const size_t OFF_BS   = OFF_BW   + 524288;       // 196608
  const size_t OFF_BR   = OFF_BS   + 196608;       // 196608
  const size_t OFF_HF   = OFF_BR   + 196608;       // 1048576
  const size_t OFF_SENT = OFF_HF   + 1048576;      // 524288
  const size_t OFF_GXS  = OFF_SENT + 524288;       // 3145728
  const size_t OFF_HS   = OFF_GXS  + 3145728;      // 32768
  const size_t OFF_PB   = OFF_HS   + 32768;        // 17664
  const size_t OFF_GXR  = OFF_PB   + 17664;        // 98304
  const size_t OFF_DOC  = OFF_GXR  + 98304;        // 512

  short* Bw   = (short*)(ws + OFF_BW);
  short* Bs   = (short*)(ws + OFF_BS);
  short* Br   = (short*)(ws + OFF_BR);
  float* hfin = ws + OFF_HF;
  float* sent = ws + OFF_SENT;
  float* gxs  = ws + OFF_GXS;
  float* hs   = ws + OFF_HS;
  float* pb   = ws + OFF_PB;
  float* gxr  = ws + OFF_GXR;
  float* doc  = ws + OFF_DOC;

  // weight swizzles (bf16 B-fragment order)
  prep_word_w<<<512, 256, 0, stream>>>(wg_wih, wg_whh, Bw);
  prep_rnn_w<<<256, 256, 0, stream>>>(sg_whh, Bs);
  prep_rnn_w<<<256, 256, 0, stream>>>(rg_whh, Br);

  // word-level persistent bi-GRU (64 steps internal)
  word_gru<<<128, 512, 0, stream>>>(toks, embed, Bw, wg_bih, wg_bhh, hfin);
  add2k<<<512, 256, 0, stream>>>((const float4*)hfin,
      (const float4*)(hfin + (size_t)2048*256), (float4*)sent);

  // sentence level: gx GEMM (fp32) + persistent bi-GRU (32 steps internal)
  gemm_nt<<<dim3(64, 24), 256, 0, stream>>>(sent, sg_wih, gxs, 2048, 1536, 256);
  sent_gru<<<8, 512, 0, stream>>>(gxs, Bs, sg_bih, sg_bhh, hs);

  // p_batch + r_stars
  pbatch_k<<<R_, 256, 0, stream>>>(hs, uf, uf_w, pb);
  rstars_k<<<R_, 128, 0, stream>>>(pb, rfc_w1, rfc_b1, rfc_w2, rfc_b2, out);

  // review level: gx GEMM (K=276) + persistent bi-GRU + p_stars
  gemm_nt<<<dim3(2, 24), 256, 0, stream>>>(pb, rg_wih, gxr, 64, 1536, 276);
  rev_gru<<<2, 512, 0, stream>>>(gxr, Br, rg_bih, rg_bhh, doc);
  pstars_k<<<1, 128, 0, stream>>>(doc, pfc_w1, pfc_b1, pfc_w2, pfc_b2, out);
}